// Round 5
// baseline (507.684 us; speedup 1.0000x reference)
//
#include <hip/hip_runtime.h>
#include <math.h>

#define BB 2
#define NCAM 6
#define CC 256
#define HH 116
#define WW 200
#define QQ 900
#define DD 256
#define NHD 8
#define HD 32
#define HWSZ (HH*WW)

__device__ __forceinline__ float sigmoidf_(float x){ return 1.0f/(1.0f+expf(-x)); }

// ---------------- ref = sigmoid(q @ ref_w.T + ref_b)  [Q,3] ----------------
__global__ void ref_kernel(const float* __restrict__ qe, const float* __restrict__ ref_w,
                           const float* __restrict__ ref_b, float* __restrict__ ref) {
    int idx = blockIdx.x*256 + threadIdx.x;
    if (idx >= QQ*3) return;
    int q = idx/3, j = idx%3;
    float acc = ref_b[j];
    const float* qr = qe + q*DD;
    const float* wr = ref_w + j*DD;
    for (int k=0;k<DD;k++) acc += qr[k]*wr[k];
    ref[idx] = sigmoidf_(acc);
}

// ---------------- project ref points to each camera ----------------
__global__ void proj_kernel(const float* __restrict__ l2i, const float* __restrict__ ref,
        float* __restrict__ wxa, float* __restrict__ wya,
        int* __restrict__ x0a, int* __restrict__ y0a,
        int* __restrict__ maskz, int* __restrict__ inimg) {
    int idx = blockIdx.x*256+threadIdx.x;
    if (idx >= BB*NCAM*QQ) return;
    int q = idx % QQ;
    int bn = idx / QQ;   // b*NCAM+n
    float h0 = ref[q*3+0], h1 = ref[q*3+1], h2 = ref[q*3+2];
    const float* m = l2i + bn*16;
    float px = m[0]*h0+m[1]*h1+m[2]*h2+m[3];
    float py = m[4]*h0+m[5]*h1+m[6]*h2+m[7];
    float pz = m[8]*h0+m[9]*h1+m[10]*h2+m[11];
    float denom = fabsf(pz)+1e-5f;
    float sx = px/denom, sy = py/denom;
    float pnx = sx/(float)(WW-1)*2.0f-1.0f;
    float pny = sy/(float)(HH-1)*2.0f-1.0f;
    maskz[idx] = (pz > 1e-5f) ? 1 : 0;
    inimg[idx] = (fmaxf(fabsf(pnx),fabsf(pny)) < 1.0f) ? 1 : 0;
    float ix = (pnx+1.0f)*(WW*0.5f)-0.5f;
    float iy = (pny+1.0f)*(HH*0.5f)-0.5f;
    float x0f = floorf(ix), y0f = floorf(iy);
    wxa[idx] = ix-x0f; wya[idx] = iy-y0f;
    x0a[idx] = (int)x0f; y0a[idx] = (int)y0f;
}

// ---------------- bilinear gather + masked mean over cams + add q ----------------
// Per-cam metadata (weights w/ validity folded, clamped offsets) prepared once in LDS;
// all 24 corner loads issued before any use for max memory-level parallelism.
__global__ __launch_bounds__(256) void sample_kernel(const float* __restrict__ feats,
        const float* __restrict__ qe, const float* __restrict__ wxa, const float* __restrict__ wya,
        const int* __restrict__ x0a, const int* __restrict__ y0a,
        const int* __restrict__ maskz, const int* __restrict__ inimg,
        float* __restrict__ xout) {
    __shared__ float smw[NCAM][4];
    __shared__ int   smo[NCAM][4];
    __shared__ float sv[NCAM];
    int bq = blockIdx.x;
    int b = bq / QQ, q = bq % QQ;
    int c = threadIdx.x;
    float qv = qe[q*DD + c];          // prefetch (independent)
    if (threadIdx.x < NCAM) {
        int n = threadIdx.x;
        int s  = (b*NCAM+n)*QQ + q;           // matched (b,n,q) index
        int sq = b*(NCAM*QQ) + q*NCAM + n;    // reference's reshape-scrambled index
        int v = maskz[s] & inimg[sq];
        float wx = wxa[s], wy = wya[s];
        int x0 = x0a[s], y0 = y0a[s];
        int x1 = x0+1, y1 = y0+1;
        bool x0ok = ((unsigned)x0 < (unsigned)WW);
        bool x1ok = ((unsigned)x1 < (unsigned)WW);
        bool y0ok = ((unsigned)y0 < (unsigned)HH);
        bool y1ok = ((unsigned)y1 < (unsigned)HH);
        int cx0 = x0ok ? x0 : 0, cx1 = x1ok ? x1 : 0;
        int cy0 = y0ok ? y0 : 0, cy1 = y1ok ? y1 : 0;
        float fv = v ? 1.f : 0.f;
        smw[n][0] = (y0ok && x0ok) ? fv*(1.f-wx)*(1.f-wy) : 0.f;
        smw[n][1] = (y0ok && x1ok) ? fv*wx*(1.f-wy)       : 0.f;
        smw[n][2] = (y1ok && x0ok) ? fv*(1.f-wx)*wy       : 0.f;
        smw[n][3] = (y1ok && x1ok) ? fv*wx*wy             : 0.f;
        smo[n][0] = cy0*WW + cx0;
        smo[n][1] = cy0*WW + cx1;
        smo[n][2] = cy1*WW + cx0;
        smo[n][3] = cy1*WW + cx1;
        sv[n] = fv;
    }
    __syncthreads();
    float wreg[NCAM][4];
    float vreg[NCAM][4];
    #pragma unroll
    for (int n = 0; n < NCAM; n++) {
        const float* fb = feats + ((size_t)(b*NCAM+n)*CC + c)*HWSZ;
        #pragma unroll
        for (int k = 0; k < 4; k++) {
            float w = smw[n][k];
            wreg[n][k] = w;
            vreg[n][k] = 0.f;
            if (w != 0.f) vreg[n][k] = fb[smo[n][k]];
        }
    }
    float sum = 0.f;
    #pragma unroll
    for (int n = 0; n < NCAM; n++)
        #pragma unroll
        for (int k = 0; k < 4; k++)
            sum += wreg[n][k]*vreg[n][k];
    float cf = sv[0]+sv[1]+sv[2]+sv[3]+sv[4]+sv[5];
    float inv = 1.0f / fmaxf(cf, 1.0f);
    xout[(size_t)bq*DD + c] = qv + sum*inv;
}

// ---------------- tiled SGEMM: C[M,N] = A[M,K] @ Wt[N,K]^T + bias[N] ----------------
#define TILE 64
#define BKK 16
__global__ __launch_bounds__(256) void sgemm_nt(const float* __restrict__ A,
        const float* __restrict__ Bw, const float* __restrict__ bias,
        float* __restrict__ Cm, int M, int N, int K) {
    __shared__ float As[BKK][TILE];
    __shared__ float Bs[BKK][TILE];
    int tid = threadIdx.x;
    int m0 = blockIdx.y * TILE, n0 = blockIdx.x * TILE;
    float acc[4][4] = {};
    int tx = tid & 15, ty = tid >> 4;
    for (int k0 = 0; k0 < K; k0 += BKK) {
        #pragma unroll
        for (int i = 0; i < 4; i++) {
            int idx = tid + i * 256;
            int m = idx >> 4;
            int k = idx & 15;
            int gm = m0 + m;
            As[k][m] = (gm < M) ? A[(size_t)gm * K + k0 + k] : 0.0f;
            int gn = n0 + m;
            Bs[k][m] = (gn < N) ? Bw[(size_t)gn * K + k0 + k] : 0.0f;
        }
        __syncthreads();
        #pragma unroll
        for (int k = 0; k < BKK; k++) {
            float a[4], bb[4];
            #pragma unroll
            for (int i = 0; i < 4; i++) a[i] = As[k][ty*4+i];
            #pragma unroll
            for (int j = 0; j < 4; j++) bb[j] = Bs[k][tx*4+j];
            #pragma unroll
            for (int i = 0; i < 4; i++)
                #pragma unroll
                for (int j = 0; j < 4; j++)
                    acc[i][j] += a[i] * bb[j];
        }
        __syncthreads();
    }
    for (int i = 0; i < 4; i++) {
        int gm = m0 + ty*4 + i;
        if (gm >= M) continue;
        for (int j = 0; j < 4; j++) {
            int gn = n0 + tx*4 + j;
            if (gn < N) Cm[(size_t)gm * N + gn] = acc[i][j] + bias[gn];
        }
    }
}

// ---------------- flash-style attention v2 (fixed): block per (b, h, 64-query tile) ----
// Score fragment: 4q x 4k (ty*4 rows, tx*4 cols over 64x64).
// PV fragment:    4q x 2d (ty*4 rows, tx*2 cols over 64x32)  -- d stays within HD=32!
// No max-subtraction: scores are O(1) (softmax shift-invariant; exp can't overflow).
#define QT2 64
#define KT2 64
#define NQB2 15
__global__ __launch_bounds__(256) void attn_flash2(const float* __restrict__ qkv,
                                                   float* __restrict__ attn_out) {
    __shared__ __align__(16) float Qs[32][72];   // [d][q]
    __shared__ __align__(16) float Ks[32][72];   // [d][k]
    __shared__ __align__(16) float Vs[64][36];   // [k][d]
    __shared__ __align__(16) float Ps[64][76];   // [q][k]
    int blk = blockIdx.x;
    int qb = blk % NQB2;
    int h  = (blk / NQB2) % NHD;
    int b  = blk / (NQB2*NHD);
    int q0 = qb * QT2;
    int tid = threadIdx.x;
    int tx = tid & 15, ty = tid >> 4;

    // load Q tile transposed: Qs[d][q]
    {
        int q = tid >> 2;                 // 0..63
        int dseg = (tid & 3) * 8;
        int gq = q0 + q; if (gq > QQ-1) gq = QQ-1;
        const float* qp = qkv + ((size_t)(b*QQ+gq))*768 + h*HD + dseg;
        float4 f0 = *(const float4*)(qp);
        float4 f1 = *(const float4*)(qp+4);
        Qs[dseg+0][q]=f0.x; Qs[dseg+1][q]=f0.y; Qs[dseg+2][q]=f0.z; Qs[dseg+3][q]=f0.w;
        Qs[dseg+4][q]=f1.x; Qs[dseg+5][q]=f1.y; Qs[dseg+6][q]=f1.z; Qs[dseg+7][q]=f1.w;
    }

    float O[4][2] = {};
    float l[4] = {};
    const float scale = 0.17677669529663689f; // 1/sqrt(32)

    for (int k0 = 0; k0 < QQ; k0 += KT2) {
        {
            int k = tid >> 2;             // 0..63
            int dseg = (tid & 3) * 8;
            int gk = k0 + k; if (gk > QQ-1) gk = QQ-1;
            const float* kp = qkv + ((size_t)(b*QQ+gk))*768 + 256 + h*HD + dseg;
            float4 f0 = *(const float4*)(kp);
            float4 f1 = *(const float4*)(kp+4);
            Ks[dseg+0][k]=f0.x; Ks[dseg+1][k]=f0.y; Ks[dseg+2][k]=f0.z; Ks[dseg+3][k]=f0.w;
            Ks[dseg+4][k]=f1.x; Ks[dseg+5][k]=f1.y; Ks[dseg+6][k]=f1.z; Ks[dseg+7][k]=f1.w;
            const float* vp = qkv + ((size_t)(b*QQ+gk))*768 + 512 + h*HD + dseg;
            *(float4*)(&Vs[k][dseg])   = *(const float4*)(vp);
            *(float4*)(&Vs[k][dseg+4]) = *(const float4*)(vp+4);
        }
        __syncthreads();

        // scores: 4q x 4k register fragment
        float acc[4][4] = {};
        #pragma unroll
        for (int d = 0; d < 32; d++) {
            float4 qv = *(const float4*)(&Qs[d][ty*4]);
            float4 kv = *(const float4*)(&Ks[d][tx*4]);
            acc[0][0]+=qv.x*kv.x; acc[0][1]+=qv.x*kv.y; acc[0][2]+=qv.x*kv.z; acc[0][3]+=qv.x*kv.w;
            acc[1][0]+=qv.y*kv.x; acc[1][1]+=qv.y*kv.y; acc[1][2]+=qv.y*kv.z; acc[1][3]+=qv.y*kv.w;
            acc[2][0]+=qv.z*kv.x; acc[2][1]+=qv.z*kv.y; acc[2][2]+=qv.z*kv.z; acc[2][3]+=qv.z*kv.w;
            acc[3][0]+=qv.w*kv.x; acc[3][1]+=qv.w*kv.y; acc[3][2]+=qv.w*kv.z; acc[3][3]+=qv.w*kv.w;
        }
        // exp + tail mask + row-sum across tx(16)
        #pragma unroll
        for (int i = 0; i < 4; i++) {
            float e[4];
            float rs = 0.f;
            #pragma unroll
            for (int j = 0; j < 4; j++) {
                int gk = k0 + tx*4 + j;
                float v = (gk < QQ) ? expf(acc[i][j]*scale) : 0.f;
                e[j] = v; rs += v;
            }
            #pragma unroll
            for (int m = 1; m < 16; m <<= 1) rs += __shfl_xor(rs, m, 16);
            l[i] += rs;
            *(float4*)(&Ps[ty*4+i][tx*4]) = make_float4(e[0],e[1],e[2],e[3]);
        }
        __syncthreads();

        // PV: O[4q][2d] accumulate (d = tx*2, within HD=32)
        #pragma unroll
        for (int k4 = 0; k4 < 16; k4++) {
            float4 p[4];
            float2 v[4];
            #pragma unroll
            for (int i = 0; i < 4; i++) p[i] = *(const float4*)(&Ps[ty*4+i][k4*4]);
            #pragma unroll
            for (int r = 0; r < 4; r++) v[r] = *(const float2*)(&Vs[k4*4+r][tx*2]);
            #pragma unroll
            for (int i = 0; i < 4; i++) {
                O[i][0] += p[i].x*v[0].x + p[i].y*v[1].x + p[i].z*v[2].x + p[i].w*v[3].x;
                O[i][1] += p[i].x*v[0].y + p[i].y*v[1].y + p[i].z*v[2].y + p[i].w*v[3].y;
            }
        }
        __syncthreads();
    }

    #pragma unroll
    for (int i = 0; i < 4; i++) {
        int gq = q0 + ty*4 + i;
        if (gq < QQ) {
            float inv = 1.0f / l[i];
            float2 o2 = make_float2(O[i][0]*inv, O[i][1]*inv);
            *(float2*)(attn_out + ((size_t)(b*QQ+gq))*DD + h*HD + tx*2) = o2;
        }
    }
}

// ---------------- layernorm + cls/box heads ----------------
__global__ __launch_bounds__(256) void final_kernel(const float* __restrict__ o,
    const float* __restrict__ norm_w, const float* __restrict__ norm_b,
    const float* __restrict__ cls_w, const float* __restrict__ cls_b,
    const float* __restrict__ box_w, const float* __restrict__ box_b,
    float* __restrict__ out) {
    __shared__ float s_xn[DD];
    __shared__ float red[8];
    int bq = blockIdx.x;
    int t = threadIdx.x;
    float val = o[(size_t)bq*DD + t];
    float v1 = val, v2 = val*val;
    for (int off=32; off>0; off>>=1) { v1 += __shfl_down(v1, off); v2 += __shfl_down(v2, off); }
    if ((t & 63) == 0) { red[t>>6] = v1; red[4 + (t>>6)] = v2; }
    __syncthreads();
    float ssum = red[0]+red[1]+red[2]+red[3];
    float ssq  = red[4]+red[5]+red[6]+red[7];
    float mu = ssum / (float)DD;
    float var = ssq / (float)DD - mu*mu;
    float inv = 1.0f / sqrtf(var + 1e-5f);
    s_xn[t] = (val - mu)*inv*norm_w[t] + norm_b[t];
    __syncthreads();
    int j = t >> 5, lane = t & 31;
    const float* wrow = (j < 2) ? (cls_w + j*DD) : (box_w + (j-2)*DD);
    float acc = 0.f;
    for (int k=lane; k<DD; k+=32) acc += s_xn[k]*wrow[k];
    for (int off=16; off>0; off>>=1) acc += __shfl_down(acc, off, 32);
    if (lane == 0) {
        if (j < 2) {
            out[(size_t)bq*2 + j] = acc + cls_b[j];
        } else {
            int jj = j-2;
            float v = acc + box_b[jj];
            if (jj < 3) v = sigmoidf_(v);
            out[BB*QQ*2 + (size_t)bq*6 + jj] = v;
        }
    }
}

extern "C" void kernel_launch(void* const* d_in, const int* in_sizes, int n_in,
                              void* d_out, int out_size, void* d_ws, size_t ws_size,
                              hipStream_t stream) {
    const float* feats = (const float*)d_in[0];
    const float* l2i   = (const float*)d_in[1];
    const float* qe    = (const float*)d_in[2];
    const float* ref_w = (const float*)d_in[3];
    const float* ref_b = (const float*)d_in[4];
    const float* ipw   = (const float*)d_in[5];
    const float* ipb   = (const float*)d_in[6];
    const float* opw   = (const float*)d_in[7];
    const float* opb   = (const float*)d_in[8];
    const float* nw    = (const float*)d_in[9];
    const float* nb    = (const float*)d_in[10];
    const float* clsw  = (const float*)d_in[11];
    const float* clsb  = (const float*)d_in[12];
    const float* boxw  = (const float*)d_in[13];
    const float* boxb  = (const float*)d_in[14];
    float* out = (float*)d_out;
    float* ws = (float*)d_ws;

    float* ref   = ws;                         // 2700
    float* wxa   = ws + 2700;                  // 10800
    float* wya   = wxa + 10800;                // 10800
    int*   x0a   = (int*)(wya + 10800);        // 10800
    int*   y0a   = x0a + 10800;                // 10800
    int*   maskz = y0a + 10800;                // 10800
    int*   inimg = maskz + 10800;              // 10800
    float* x     = (float*)(inimg + 10800);    // 1800*256
    float* qkv   = x + 460800;                 // 1800*768
    float* attn  = qkv + 1382400;              // 1800*256
    float* oproj = attn + 460800;              // 1800*256

    ref_kernel<<<(QQ*3+255)/256, 256, 0, stream>>>(qe, ref_w, ref_b, ref);
    proj_kernel<<<(BB*NCAM*QQ+255)/256, 256, 0, stream>>>(l2i, ref, wxa, wya, x0a, y0a, maskz, inimg);
    sample_kernel<<<BB*QQ, 256, 0, stream>>>(feats, qe, wxa, wya, x0a, y0a, maskz, inimg, x);
    sgemm_nt<<<dim3(768/TILE, (BB*QQ+TILE-1)/TILE), 256, 0, stream>>>(x, ipw, ipb, qkv, BB*QQ, 768, 256);
    attn_flash2<<<BB*NHD*NQB2, 256, 0, stream>>>(qkv, attn);
    sgemm_nt<<<dim3(256/TILE, (BB*QQ+TILE-1)/TILE), 256, 0, stream>>>(attn, opw, opb, oproj, BB*QQ, 256, 256);
    final_kernel<<<BB*QQ, 256, 0, stream>>>(oproj, nw, nb, clsw, clsb, boxw, boxb, out);
}